// Round 8
// baseline (112.726 us; speedup 1.0000x reference)
//
#include <hip/hip_runtime.h>

// ---------------- constants ----------------
// B=16, CIN=256, COUT=256, H=W=64, K=3, SDIM=128
// Separable reformulation:
//   out[b,co,p] = demod[b,co] * sum_{t,ci} wsh[t,co,ci] * y[b,ci,p+shift(t)]
//   wsh = conv_scale * w  (batch-independent!),  y = s[b,ci] * x[b,ci,p]
//   demod[b,co] = rsqrt( sum_ci G[co,ci] * s[b,ci]^2 + 1e-8 ),  G = sum_t wsh^2
// ws layout (bytes):
//   xpad  bf16 [16][66][66][256] : 0          .. 35,684,352   (holds y, padded NHWC)
//   wsh   bf16 [9][256][256]     : 35,684,352 .. 36,864,000
//   s     f32  [16][256]         : 36,864,000 .. 36,880,384
//   G     f32  [256][256]        : 36,880,384 .. 37,142,528
//   demod f32  [16][256]         : 37,142,528 .. 37,158,912

#define WSH_OFF    35684352
#define S_OFF      36864000
#define G_OFF      36880384
#define DEMOD_OFF  37142528

typedef __attribute__((ext_vector_type(8))) short bf16x8;
typedef __attribute__((ext_vector_type(16))) float f32x16;
typedef __attribute__((ext_vector_type(4))) int i32x4;

#define GLOAD_LDS16(g, l)                                                        \
  __builtin_amdgcn_global_load_lds(                                              \
      (const __attribute__((address_space(1))) void*)(g),                        \
      (__attribute__((address_space(3))) void*)(l), 16, 0, 0)

__device__ __forceinline__ unsigned short f2bf(float f) {
  unsigned int u = __builtin_bit_cast(unsigned int, f);
  u += 0x7FFFu + ((u >> 16) & 1u);  // round-to-nearest-even
  return (unsigned short)(u >> 16);
}

// ---------------- kernel 1: style s[b][i]  +  shared weights & G ----------------
__global__ void prep1_k(const float* __restrict__ c_trg,
                        const float* __restrict__ style_w,
                        const float* __restrict__ style_b,
                        const float* __restrict__ weight,
                        float* __restrict__ s,
                        short* __restrict__ wsh,
                        float* __restrict__ G) {
  const int blk = blockIdx.x;
  const int tid = threadIdx.x;
  if (blk < 16) {
    const int b = blk;
    const float* ct = c_trg + b * 128;
    const float* sw = style_w + tid * 128;
    float acc = 0.f;
#pragma unroll 4
    for (int d = 0; d < 128; ++d) acc += ct[d] * sw[d];
    s[b * 256 + tid] = acc * 0.08838834764831845f + style_b[tid];  // 1/sqrt(128)
  } else {
    const int idx = (blk - 16) * 256 + tid;  // co*256+ci
    const float* wsrc = weight + idx * 9;    // 9 contiguous taps
    float g = 0.f;
#pragma unroll
    for (int t = 0; t < 9; ++t) {
      float v = wsrc[t] * 0.020833333333333332f;  // 1/sqrt(2304)
      g += v * v;
      wsh[t * 65536 + idx] = (short)f2bf(v);
    }
    G[idx] = g;
  }
}

// ---------------- kernel 2: y = s*x transpose + border zero + demod (fused grid) ----
__global__ void xpose_k(const float* __restrict__ x,
                        const float* __restrict__ s,
                        const float* __restrict__ G,
                        short* __restrict__ xpad,
                        float* __restrict__ demod) {
  __shared__ float tile[64][65];
  const int bid = blockIdx.x;
  const int tid = threadIdx.x;
  if (bid >= 4112) {
    // demod: block = b*256+co
    const int id = bid - 4112;
    const int b = id >> 8, co = id & 255;
    const float sv = s[b * 256 + tid];
    float ss = G[co * 256 + tid] * sv * sv;
#pragma unroll
    for (int o = 32; o; o >>= 1) ss += __shfl_down(ss, o);
    __shared__ float red[4];
    if ((tid & 63) == 0) red[tid >> 6] = ss;
    __syncthreads();
    if (tid == 0) demod[id] = rsqrtf(red[0] + red[1] + red[2] + red[3] + 1e-8f);
    return;
  }
  if (bid >= 4096) {
    const int b = bid - 4096;
    char* base = (char*)xpad + b * 66 * 66 * 512;
    const i32x4 z = {0, 0, 0, 0};
    for (int i = tid; i < 4224; i += 256) {
      const int r = i >= 2112;
      const int off = r * (65 * 66 * 512) + (i - r * 2112) * 16;
      *(i32x4*)(base + off) = z;
    }
    for (int i = tid; i < 4096; i += 256) {
      const int h = 1 + (i >> 6);
      const int side = (i >> 5) & 1;
      const int j = i & 31;
      *(i32x4*)(base + (h * 66 + side * 65) * 512 + j * 16) = z;
    }
    return;
  }
  const int ct = bid & 3;
  const int h = (bid >> 2) & 63;
  const int b = bid >> 8;
  const int w = tid & 63, cl = tid >> 6;
  const float* src = x + ((b * 256 + ct * 64) * 64 + h) * 64;
#pragma unroll
  for (int i = 0; i < 16; ++i) {
    int c = i * 4 + cl;
    tile[c][w] = src[c * 4096 + w];
  }
  const int cp = tid & 31;
  const float s0 = s[b * 256 + ct * 64 + cp * 2];
  const float s1 = s[b * 256 + ct * 64 + cp * 2 + 1];
  __syncthreads();
  short* dst = xpad + ((b * 66 + h + 1) * 66 + 1) * 256 + ct * 64;
#pragma unroll
  for (int i = 0; i < 8; ++i) {
    int idx = i * 256 + tid;
    int w2 = idx >> 5;  // 0..63
    unsigned int u = (unsigned int)f2bf(tile[cp * 2][w2] * s0) |
                     ((unsigned int)f2bf(tile[cp * 2 + 1][w2] * s1) << 16);
    *(unsigned int*)(dst + w2 * 256 + cp * 2) = u;
  }
}

// ---------------- kernel 3: implicit-GEMM conv, 256x256, BK=64, drift + 32x32 MFMA ---
// 512 thr = 8 waves (2M x 4N), wave tile 128x64. LDS = 2 dbuf x (A 32K + B 32K).
// 36 K-tiles (tap 0..8 x cc 0..3). ONE sync point per tile (vmcnt(0)+barrier+SB);
// NO intra-tile pins: the compiler emits fine-grained lgkmcnt(N) so each MFMA
// starts as soon as its own ds_reads land (m97-asm behavior), overlapping the
// read burst tail. mfma_f32_32x32x16_bf16: half the instructions, 2495-TF shape.
// Staging of tile t+1 (A at front, B mid-tile) keeps the vmem queue busy;
// stage targets buf (t+1)&1 = tile t-1's buffer (reads retired pre-barrier).
// T1: XCD swizzle (grid 256) -> 2 samples per XCD L2.
// T2: XOR swizzle byte ^= ((row&7)<<4): linear LDS dest, inverse-swizzled
//     global source, swizzled ds_read. 32x32 A-frag: row=lane&31, k-half=lane>>5
//     -> row&7 == lane&7, same XOR key as 16x16 layout (measured 0 conflicts).
__global__ __launch_bounds__(512, 2) void conv_k(const short* __restrict__ xpad,
                                                 const short* __restrict__ wsh,
                                                 const float* __restrict__ demod,
                                                 float* __restrict__ out) {
  extern __shared__ __align__(16) char lds[];  // 131072 B

  const int tid = threadIdx.x;
  const int lane = tid & 63;
  const int wid = tid >> 6;
  const int wm = wid >> 2;   // 0..1 : cout half
  const int wn = wid & 3;    // 0..3 : pixel quarter (output row r0+wn)

  const int orig = blockIdx.x;
  const int bid = (orig & 7) * 32 + (orig >> 3);  // T1
  const int b = bid >> 4;
  const int r0 = (bid & 15) * 4;  // 4 output rows per block

  // staging: per K-tile 8 x 16B loads/thread (A j0-3, B j0-3).
  // load j covers LDS rows j*64 + t3, byte col (tid&7)*16 (linear dest);
  // source col pre-swizzled: c16 ^ ((row&7)<<4), row&7 == t3&7.
  const int t3 = tid >> 3;
  const int c16 = (tid & 7) * 16;
  const int swzc = c16 ^ ((t3 & 7) << 4);
  int aO[4], bO[4];
#pragma unroll
  for (int j = 0; j < 4; ++j) {
    aO[j] = (j * 64 + t3) * 512 + swzc;                   // + tap*131072 + cc*128
    bO[j] = ((b * 66 + r0 + j) * 66 + t3) * 512 + swzc;   // + (dh*66+dw)*512 + cc*128
  }
  const char* wB = (const char*)wsh;
  const char* xB = (const char*)xpad;

  auto stageA = [&](int ts) {
    const int tap = ts >> 2, cc = ts & 3;
    const int aAdd = tap * 131072 + cc * 128;
    char* d = lds + (ts & 1) * 65536;
#pragma unroll
    for (int j = 0; j < 4; ++j)
      GLOAD_LDS16(wB + aAdd + aO[j], d + j * 8192 + tid * 16);
  };
  auto stageB = [&](int ts) {
    const int tap = ts >> 2, cc = ts & 3;
    const int dh = (tap * 11) >> 5;  // tap/3
    const int bAdd = (dh * 66 + (tap - dh * 3)) * 512 + cc * 128;
    char* d = lds + (ts & 1) * 65536 + 32768;
#pragma unroll
    for (int j = 0; j < 4; ++j)
      GLOAD_LDS16(xB + bAdd + bO[j], d + j * 8192 + tid * 16);
  };

  // 32x32x16 read addressing. Frag: row = (tile-row base) + (lane&31),
  // 16B col within 128B row = kk*32 + (lane>>5)*16, XORed by (row&7)<<4.
  // row&7 == lane&7; col bits {4}={lane>>5}, {5,6}={kk} are disjoint.
  const int xk = (lane & 7) << 4;
  int colx[4];
#pragma unroll
  for (int kk = 0; kk < 4; ++kk)
    colx[kk] = ((kk * 32) ^ (xk & 0x60)) + (((lane >> 5) << 4) ^ (xk & 16));
  const int aRdBase = (wm * 128 + (lane & 31)) * 128;            // A region
  const int bRdBase = 32768 + (wn * 64 + (lane & 31)) * 128;     // B region

  f32x16 acc[4][2] = {};

  stageA(0);
  stageB(0);

  for (int t = 0; t < 36; ++t) {
    // single sync point per K-tile
    asm volatile("s_waitcnt vmcnt(0)" ::: "memory");
    __builtin_amdgcn_s_barrier();
    __builtin_amdgcn_sched_barrier(0);

    const char* Ab = lds + (t & 1) * 65536 + aRdBase;
    const char* Bb = lds + (t & 1) * 65536 + bRdBase;
    bf16x8 a01[2][4], a23[2][4], b0[4], b1[4];

    // group 1: A(mt0,1) + B(nt0) reads; stage A(t+1); 8 MFMA
#pragma unroll
    for (int kk = 0; kk < 4; ++kk) {
      a01[0][kk] = *(const bf16x8*)(Ab + 0 * 4096 + colx[kk]);
      a01[1][kk] = *(const bf16x8*)(Ab + 1 * 4096 + colx[kk]);
      b0[kk]     = *(const bf16x8*)(Bb + 0 * 4096 + colx[kk]);
    }
    if (t + 1 < 36) stageA(t + 1);
    __builtin_amdgcn_s_setprio(1);
#pragma unroll
    for (int kk = 0; kk < 4; ++kk) {
      acc[0][0] = __builtin_amdgcn_mfma_f32_32x32x16_bf16(a01[0][kk], b0[kk], acc[0][0], 0, 0, 0);
      acc[1][0] = __builtin_amdgcn_mfma_f32_32x32x16_bf16(a01[1][kk], b0[kk], acc[1][0], 0, 0, 0);
    }
    __builtin_amdgcn_s_setprio(0);

    // group 2: B(nt1) reads; stage B(t+1); 8 MFMA
#pragma unroll
    for (int kk = 0; kk < 4; ++kk)
      b1[kk] = *(const bf16x8*)(Bb + 1 * 4096 + colx[kk]);
    if (t + 1 < 36) stageB(t + 1);
    __builtin_amdgcn_s_setprio(1);
#pragma unroll
    for (int kk = 0; kk < 4; ++kk) {
      acc[0][1] = __builtin_amdgcn_mfma_f32_32x32x16_bf16(a01[0][kk], b1[kk], acc[0][1], 0, 0, 0);
      acc[1][1] = __builtin_amdgcn_mfma_f32_32x32x16_bf16(a01[1][kk], b1[kk], acc[1][1], 0, 0, 0);
    }
    __builtin_amdgcn_s_setprio(0);

    // group 3: A(mt2,3) reads; 16 MFMA
#pragma unroll
    for (int kk = 0; kk < 4; ++kk) {
      a23[0][kk] = *(const bf16x8*)(Ab + 2 * 4096 + colx[kk]);
      a23[1][kk] = *(const bf16x8*)(Ab + 3 * 4096 + colx[kk]);
    }
    __builtin_amdgcn_s_setprio(1);
#pragma unroll
    for (int kk = 0; kk < 4; ++kk) {
      acc[2][0] = __builtin_amdgcn_mfma_f32_32x32x16_bf16(a23[0][kk], b0[kk], acc[2][0], 0, 0, 0);
      acc[3][0] = __builtin_amdgcn_mfma_f32_32x32x16_bf16(a23[1][kk], b0[kk], acc[3][0], 0, 0, 0);
      acc[2][1] = __builtin_amdgcn_mfma_f32_32x32x16_bf16(a23[0][kk], b1[kk], acc[2][1], 0, 0, 0);
      acc[3][1] = __builtin_amdgcn_mfma_f32_32x32x16_bf16(a23[1][kk], b1[kk], acc[3][1], 0, 0, 0);
    }
    __builtin_amdgcn_s_setprio(0);
    asm volatile("" ::: "memory");
  }

  // epilogue: scale by demod[b][cout], store fp32 NCHW.
  // 32x32 C/D: col(pixel) = lane&31, row(cout) = (r&3) + 8*(r>>2) + 4*(lane>>5).
  const int w = lane & 31;
  const int rHi = (lane >> 5) * 4;
  const int h = r0 + wn;
#pragma unroll
  for (int mt = 0; mt < 4; ++mt) {
#pragma unroll
    for (int nt = 0; nt < 2; ++nt) {
      const int ww = nt * 32 + w;
#pragma unroll
      for (int r = 0; r < 16; ++r) {
        const int co = wm * 128 + mt * 32 + (r & 3) + 8 * (r >> 2) + rHi;
        const float dm = demod[(b << 8) + co];
        out[((((b << 8) + co) << 12)) + (h << 6) + ww] = acc[mt][nt][r] * dm;
      }
    }
  }
}

// ---------------- launcher ----------------
extern "C" void kernel_launch(void* const* d_in, const int* in_sizes, int n_in,
                              void* d_out, int out_size, void* d_ws, size_t ws_size,
                              hipStream_t stream) {
  const float* x       = (const float*)d_in[0];
  // d_in[1] = c_src (unused by reference)
  const float* c_trg   = (const float*)d_in[2];
  const float* style_w = (const float*)d_in[3];
  const float* style_b = (const float*)d_in[4];
  const float* weight  = (const float*)d_in[5];
  float* out = (float*)d_out;

  char* ws = (char*)d_ws;
  short* xpad  = (short*)(ws);
  short* wsh   = (short*)(ws + WSH_OFF);
  float* s     = (float*)(ws + S_OFF);
  float* G     = (float*)(ws + G_OFF);
  float* demod = (float*)(ws + DEMOD_OFF);

  hipFuncSetAttribute((const void*)conv_k,
                      hipFuncAttributeMaxDynamicSharedMemorySize, 131072);

  prep1_k<<<272, 256, 0, stream>>>(c_trg, style_w, style_b, weight, s, wsh, G);
  xpose_k<<<8208, 256, 0, stream>>>(x, s, G, xpad, demod);
  conv_k<<<256, 512, 131072, stream>>>(xpad, wsh, demod, out);
}

// Round 9
// 109.145 us; speedup vs baseline: 1.0328x; 1.0328x over previous
//
#include <hip/hip_runtime.h>

// ---------------- constants ----------------
// B=16, CIN=256, COUT=256, H=W=64, K=3, SDIM=128
// Separable reformulation:
//   out[b,co,p] = demod[b,co] * sum_{t,ci} wsh[t,co,ci] * y[b,ci,p+shift(t)]
//   wsh = conv_scale * w  (batch-independent!),  y = s[b,ci] * x[b,ci,p]
//   demod[b,co] = rsqrt( sum_ci G[co,ci] * s[b,ci]^2 + 1e-8 ),  G = sum_t wsh^2
// ws layout (bytes):
//   xpad  bf16 [16][66][66][256] : 0          .. 35,684,352   (holds y, padded NHWC)
//   wsh   bf16 [9][256][256]     : 35,684,352 .. 36,864,000
//   s     f32  [16][256]         : 36,864,000 .. 36,880,384
//   G     f32  [256][256]        : 36,880,384 .. 37,142,528
//   demod f32  [16][256]         : 37,142,528 .. 37,158,912

#define WSH_OFF    35684352
#define S_OFF      36864000
#define G_OFF      36880384
#define DEMOD_OFF  37142528

typedef __attribute__((ext_vector_type(8))) short bf16x8;
typedef __attribute__((ext_vector_type(4))) float f32x4;
typedef __attribute__((ext_vector_type(4))) int i32x4;

#define GLOAD_LDS16(g, l)                                                        \
  __builtin_amdgcn_global_load_lds(                                              \
      (const __attribute__((address_space(1))) void*)(g),                        \
      (__attribute__((address_space(3))) void*)(l), 16, 0, 0)

__device__ __forceinline__ unsigned short f2bf(float f) {
  unsigned int u = __builtin_bit_cast(unsigned int, f);
  u += 0x7FFFu + ((u >> 16) & 1u);  // round-to-nearest-even
  return (unsigned short)(u >> 16);
}

// ---------------- kernel 1: style s[b][i]  +  shared weights & G ----------------
__global__ void prep1_k(const float* __restrict__ c_trg,
                        const float* __restrict__ style_w,
                        const float* __restrict__ style_b,
                        const float* __restrict__ weight,
                        float* __restrict__ s,
                        short* __restrict__ wsh,
                        float* __restrict__ G) {
  const int blk = blockIdx.x;
  const int tid = threadIdx.x;
  if (blk < 16) {
    const int b = blk;
    const float* ct = c_trg + b * 128;
    const float* sw = style_w + tid * 128;
    float acc = 0.f;
#pragma unroll 4
    for (int d = 0; d < 128; ++d) acc += ct[d] * sw[d];
    s[b * 256 + tid] = acc * 0.08838834764831845f + style_b[tid];  // 1/sqrt(128)
  } else {
    const int idx = (blk - 16) * 256 + tid;  // co*256+ci
    const float* wsrc = weight + idx * 9;    // 9 contiguous taps
    float g = 0.f;
#pragma unroll
    for (int t = 0; t < 9; ++t) {
      float v = wsrc[t] * 0.020833333333333332f;  // 1/sqrt(2304)
      g += v * v;
      wsh[t * 65536 + idx] = (short)f2bf(v);
    }
    G[idx] = g;
  }
}

// ---------------- kernel 2: y = s*x transpose + border zero + demod (fused grid) ----
__global__ void xpose_k(const float* __restrict__ x,
                        const float* __restrict__ s,
                        const float* __restrict__ G,
                        short* __restrict__ xpad,
                        float* __restrict__ demod) {
  __shared__ float tile[64][65];
  const int bid = blockIdx.x;
  const int tid = threadIdx.x;
  if (bid >= 4112) {
    // demod: block = b*256+co
    const int id = bid - 4112;
    const int b = id >> 8, co = id & 255;
    const float sv = s[b * 256 + tid];
    float ss = G[co * 256 + tid] * sv * sv;
#pragma unroll
    for (int o = 32; o; o >>= 1) ss += __shfl_down(ss, o);
    __shared__ float red[4];
    if ((tid & 63) == 0) red[tid >> 6] = ss;
    __syncthreads();
    if (tid == 0) demod[id] = rsqrtf(red[0] + red[1] + red[2] + red[3] + 1e-8f);
    return;
  }
  if (bid >= 4096) {
    const int b = bid - 4096;
    char* base = (char*)xpad + b * 66 * 66 * 512;
    const i32x4 z = {0, 0, 0, 0};
    for (int i = tid; i < 4224; i += 256) {
      const int r = i >= 2112;
      const int off = r * (65 * 66 * 512) + (i - r * 2112) * 16;
      *(i32x4*)(base + off) = z;
    }
    for (int i = tid; i < 4096; i += 256) {
      const int h = 1 + (i >> 6);
      const int side = (i >> 5) & 1;
      const int j = i & 31;
      *(i32x4*)(base + (h * 66 + side * 65) * 512 + j * 16) = z;
    }
    return;
  }
  const int ct = bid & 3;
  const int h = (bid >> 2) & 63;
  const int b = bid >> 8;
  const int w = tid & 63, cl = tid >> 6;
  const float* src = x + ((b * 256 + ct * 64) * 64 + h) * 64;
#pragma unroll
  for (int i = 0; i < 16; ++i) {
    int c = i * 4 + cl;
    tile[c][w] = src[c * 4096 + w];
  }
  const int cp = tid & 31;
  const float s0 = s[b * 256 + ct * 64 + cp * 2];
  const float s1 = s[b * 256 + ct * 64 + cp * 2 + 1];
  __syncthreads();
  short* dst = xpad + ((b * 66 + h + 1) * 66 + 1) * 256 + ct * 64;
#pragma unroll
  for (int i = 0; i < 8; ++i) {
    int idx = i * 256 + tid;
    int w2 = idx >> 5;  // 0..63
    unsigned int u = (unsigned int)f2bf(tile[cp * 2][w2] * s0) |
                     ((unsigned int)f2bf(tile[cp * 2 + 1][w2] * s1) << 16);
    *(unsigned int*)(dst + w2 * 256 + cp * 2) = u;
  }
}

// ---------------- kernel 3: implicit-GEMM conv, 128x128 tile, BK=64, 2 blocks/CU ----
// 256 thr = 4 waves (2M x 2N), wave tile 64x64. LDS = 2 dbuf x (A 16K + B 16K) = 64 KB
// -> TWO independent blocks per CU (4 desynced waves each): when one block sits
// at its vmcnt/barrier, the other block's MFMAs fill the pipes (m114 overlap).
// This attacks the lockstep bubble that pinned the 8-wave 256^2 variant at 47%.
// 36 K-tiles (tap 0..8 x cc 0..3). Per tile: r7's proven drift schedule:
//   top: vmcnt(0); s_barrier; sched_barrier
//   g1: ds_read A0-1,B0-1 (8); stageA(t+1); lgkmcnt(0)+SB; 8 MFMA (prio1)
//   g2: ds_read B2-3 (4);      stageB(t+1); lgkmcnt(0)+SB; 8 MFMA
//   g3: ds_read A2-3 (4);                   lgkmcnt(0)+SB; 16 MFMA
// Race-freedom: stage(t+1) targets buf (t+1)&1 = tile t-1's buffer; its reads
// were lgkmcnt-retired before each wave reached this tile's top barrier.
// T1: XCD swizzle (grid 1024 % 8 == 0).
// T2: XOR swizzle byte ^= ((row&7)<<4): linear LDS dest, inverse-swizzled global
//     source, swizzled ds_read; 16x16 frag rows span lane&15 -> 2-way max = free
//     (measured 0 conflicts; the 32x32 shape's lane&31 span is why r8 conflicted).
__global__ __launch_bounds__(256, 2) void conv_k(const short* __restrict__ xpad,
                                                 const short* __restrict__ wsh,
                                                 const float* __restrict__ demod,
                                                 float* __restrict__ out) {
  extern __shared__ __align__(16) char lds[];  // 65536 B

  const int tid = threadIdx.x;
  const int lane = tid & 63;
  const int wid = tid >> 6;
  const int wm = wid >> 1;   // 0..1 : cout 64-half within 128
  const int wn = wid & 1;    // 0..1 : pixel 64-half within 128

  const int orig = blockIdx.x;
  const int bid = (orig & 7) * 128 + (orig >> 3);  // T1 (1024 blocks)
  const int b = bid >> 6;
  const int rem = bid & 63;
  const int cout0 = (rem & 1) * 128;
  const int r0 = (rem >> 1) * 2;  // 2 output rows per block

  // staging: per K-tile 4 A-loads + 4 B-loads per thread (16 B each).
  // load j covers LDS rows j*32 + t3 (t3 = tid>>3), byte col (tid&7)*16 (linear
  // dest); source col pre-swizzled: c16 ^ ((row&7)<<4), row&7 == t3&7.
  const int t3 = tid >> 3;
  const int c16 = (tid & 7) * 16;
  const int swzc = c16 ^ ((t3 & 7) << 4);
  int aO[4], bO[4];
#pragma unroll
  for (int j = 0; j < 4; ++j) {
    aO[j] = (cout0 + j * 32 + t3) * 512 + swzc;           // + tap*131072 + cc*128
    const int p = j * 32 + t3;                            // pixel 0..127
    bO[j] = ((b * 66 + r0 + (p >> 6)) * 66 + (p & 63)) * 512 + swzc;
  }
  const char* wB = (const char*)wsh;
  const char* xB = (const char*)xpad;

  auto stageA = [&](int ts) {
    const int tap = ts >> 2, cc = ts & 3;
    const int aAdd = tap * 131072 + cc * 128;
    char* d = lds + (ts & 1) * 32768;
#pragma unroll
    for (int j = 0; j < 4; ++j)
      GLOAD_LDS16(wB + aAdd + aO[j], d + j * 4096 + tid * 16);
  };
  auto stageB = [&](int ts) {
    const int tap = ts >> 2, cc = ts & 3;
    const int dh = (tap * 11) >> 5;  // tap/3
    const int bAdd = (dh * 66 + (tap - dh * 3)) * 512 + cc * 128;
    char* d = lds + (ts & 1) * 32768 + 16384;
#pragma unroll
    for (int j = 0; j < 4; ++j)
      GLOAD_LDS16(xB + bAdd + bO[j], d + j * 4096 + tid * 16);
  };

  // T2 read side: col_read = col ^ ((row&7)<<4); row&7 == lane&7 everywhere.
  const int xall = (lane & 7) << 4;
  const int xl = xall & 0x30;
  const int xh = xall & 0x40;
  const int colR = (((lane >> 4) << 4) ^ xl);
  const int ko0 = xh;
  const int ko1 = 64 ^ xh;
  const int aRdBase = (wm * 64 + (lane & 15)) * 128 + colR;
  const int bRdBase = 16384 + (wn * 64 + (lane & 15)) * 128 + colR;

  f32x4 acc[4][4] = {};

  stageA(0);
  stageB(0);

  for (int t = 0; t < 36; ++t) {
    // single sync point per K-tile
    asm volatile("s_waitcnt vmcnt(0)" ::: "memory");
    __builtin_amdgcn_s_barrier();
    __builtin_amdgcn_sched_barrier(0);

    const char* Ab = lds + (t & 1) * 32768 + aRdBase;
    const char* Bb = lds + (t & 1) * 32768 + bRdBase;
    bf16x8 af[4][2], bq[2][2], bq2[2][2];

    // ---------- g1 : reads A0-1, B0-1 ; stage A(t+1) ; MFMA (m0-1 x n0-1) ----------
#pragma unroll
    for (int m = 0; m < 2; ++m) {
      af[m][0] = *(const bf16x8*)(Ab + m * 2048 + ko0);
      af[m][1] = *(const bf16x8*)(Ab + m * 2048 + ko1);
    }
#pragma unroll
    for (int n = 0; n < 2; ++n) {
      bq[n][0] = *(const bf16x8*)(Bb + n * 2048 + ko0);
      bq[n][1] = *(const bf16x8*)(Bb + n * 2048 + ko1);
    }
    if (t + 1 < 36) stageA(t + 1);
    asm volatile("s_waitcnt lgkmcnt(0)" ::: "memory");
    __builtin_amdgcn_sched_barrier(0);
    __builtin_amdgcn_s_setprio(1);
#pragma unroll
    for (int m = 0; m < 2; ++m)
#pragma unroll
      for (int n = 0; n < 2; ++n) {
        acc[m][n] = __builtin_amdgcn_mfma_f32_16x16x32_bf16(af[m][0], bq[n][0], acc[m][n], 0, 0, 0);
        acc[m][n] = __builtin_amdgcn_mfma_f32_16x16x32_bf16(af[m][1], bq[n][1], acc[m][n], 0, 0, 0);
      }
    __builtin_amdgcn_s_setprio(0);

    // ---------- g2 : reads B2-3 ; stage B(t+1) ; MFMA (m0-1 x n2-3) ----------------
#pragma unroll
    for (int n = 0; n < 2; ++n) {
      bq2[n][0] = *(const bf16x8*)(Bb + (n + 2) * 2048 + ko0);
      bq2[n][1] = *(const bf16x8*)(Bb + (n + 2) * 2048 + ko1);
    }
    if (t + 1 < 36) stageB(t + 1);
    asm volatile("s_waitcnt lgkmcnt(0)" ::: "memory");
    __builtin_amdgcn_sched_barrier(0);
    __builtin_amdgcn_s_setprio(1);
#pragma unroll
    for (int m = 0; m < 2; ++m)
#pragma unroll
      for (int n = 0; n < 2; ++n) {
        acc[m][n + 2] = __builtin_amdgcn_mfma_f32_16x16x32_bf16(af[m][0], bq2[n][0], acc[m][n + 2], 0, 0, 0);
        acc[m][n + 2] = __builtin_amdgcn_mfma_f32_16x16x32_bf16(af[m][1], bq2[n][1], acc[m][n + 2], 0, 0, 0);
      }
    __builtin_amdgcn_s_setprio(0);

    // ---------- g3 : reads A2-3 ; MFMA (m2-3 x n0-3) -------------------------------
#pragma unroll
    for (int m = 0; m < 2; ++m) {
      af[m + 2][0] = *(const bf16x8*)(Ab + (m + 2) * 2048 + ko0);
      af[m + 2][1] = *(const bf16x8*)(Ab + (m + 2) * 2048 + ko1);
    }
    asm volatile("s_waitcnt lgkmcnt(0)" ::: "memory");
    __builtin_amdgcn_sched_barrier(0);
    __builtin_amdgcn_s_setprio(1);
#pragma unroll
    for (int m = 0; m < 2; ++m)
#pragma unroll
      for (int n = 0; n < 2; ++n) {
        acc[m + 2][n] = __builtin_amdgcn_mfma_f32_16x16x32_bf16(af[m + 2][0], bq[n][0], acc[m + 2][n], 0, 0, 0);
        acc[m + 2][n] = __builtin_amdgcn_mfma_f32_16x16x32_bf16(af[m + 2][1], bq[n][1], acc[m + 2][n], 0, 0, 0);
        acc[m + 2][n + 2] = __builtin_amdgcn_mfma_f32_16x16x32_bf16(af[m + 2][0], bq2[n][0], acc[m + 2][n + 2], 0, 0, 0);
        acc[m + 2][n + 2] = __builtin_amdgcn_mfma_f32_16x16x32_bf16(af[m + 2][1], bq2[n][1], acc[m + 2][n + 2], 0, 0, 0);
      }
    __builtin_amdgcn_s_setprio(0);
    asm volatile("" ::: "memory");
  }

  // epilogue: scale by demod[b][cout], store fp32 NCHW.
  const int pc = lane & 15;
  const int rOff = (lane >> 4) * 4;
#pragma unroll
  for (int m = 0; m < 4; ++m) {
#pragma unroll
    for (int r = 0; r < 4; ++r) {
      const int co = cout0 + wm * 64 + m * 16 + rOff + r;
      const float dm = demod[(b << 8) + co];
      float* obase = out + (((b << 8) + co) << 12);
#pragma unroll
      for (int n = 0; n < 4; ++n) {
        const int pix = wn * 64 + n * 16 + pc;
        const int h = r0 + (pix >> 6), w = pix & 63;
        obase[(h << 6) + w] = acc[m][n][r] * dm;
      }
    }
  }
}

// ---------------- launcher ----------------
extern "C" void kernel_launch(void* const* d_in, const int* in_sizes, int n_in,
                              void* d_out, int out_size, void* d_ws, size_t ws_size,
                              hipStream_t stream) {
  const float* x       = (const float*)d_in[0];
  // d_in[1] = c_src (unused by reference)
  const float* c_trg   = (const float*)d_in[2];
  const float* style_w = (const float*)d_in[3];
  const float* style_b = (const float*)d_in[4];
  const float* weight  = (const float*)d_in[5];
  float* out = (float*)d_out;

  char* ws = (char*)d_ws;
  short* xpad  = (short*)(ws);
  short* wsh   = (short*)(ws + WSH_OFF);
  float* s     = (float*)(ws + S_OFF);
  float* G     = (float*)(ws + G_OFF);
  float* demod = (float*)(ws + DEMOD_OFF);

  hipFuncSetAttribute((const void*)conv_k,
                      hipFuncAttributeMaxDynamicSharedMemorySize, 65536);

  prep1_k<<<272, 256, 0, stream>>>(c_trg, style_w, style_b, weight, s, wsh, G);
  xpose_k<<<8208, 256, 0, stream>>>(x, s, G, xpad, demod);
  conv_k<<<1024, 256, 65536, stream>>>(xpad, wsh, demod, out);
}

// Round 10
// 96.652 us; speedup vs baseline: 1.1663x; 1.1293x over previous
//
#include <hip/hip_runtime.h>

// ---------------- constants ----------------
// B=16, CIN=256, COUT=256, H=W=64, K=3, SDIM=128
// Separable reformulation:
//   out[b,co,p] = demod[b,co] * sum_{t,ci} wsh[t,co,ci] * y[b,ci,p+shift(t)]
//   wsh = conv_scale * w  (batch-independent!),  y = s[b,ci] * x[b,ci,p]
//   demod[b,co] = rsqrt( sum_ci G[co,ci] * s[b,ci]^2 + 1e-8 ),  G = sum_t wsh^2
// ws layout (bytes):
//   xpad  bf16 [16][66][66][256] : 0          .. 35,684,352   (holds y, padded NHWC)
//   wsh   bf16 [9][256][256]     : 35,684,352 .. 36,864,000
//   s     f32  [16][256]         : 36,864,000 .. 36,880,384
//   G     f32  [256][256]        : 36,880,384 .. 37,142,528
//   demod f32  [16][256]         : 37,142,528 .. 37,158,912

#define WSH_OFF    35684352
#define S_OFF      36864000
#define G_OFF      36880384
#define DEMOD_OFF  37142528

typedef __attribute__((ext_vector_type(8))) short bf16x8;
typedef __attribute__((ext_vector_type(4))) float f32x4;
typedef __attribute__((ext_vector_type(4))) int i32x4;

#define GLOAD_LDS16(g, l)                                                        \
  __builtin_amdgcn_global_load_lds(                                              \
      (const __attribute__((address_space(1))) void*)(g),                        \
      (__attribute__((address_space(3))) void*)(l), 16, 0, 0)

__device__ __forceinline__ unsigned short f2bf(float f) {
  unsigned int u = __builtin_bit_cast(unsigned int, f);
  u += 0x7FFFu + ((u >> 16) & 1u);  // round-to-nearest-even
  return (unsigned short)(u >> 16);
}

// ---------------- kernel 1: style s[b][i]  +  shared weights & G ----------------
__global__ void prep1_k(const float* __restrict__ c_trg,
                        const float* __restrict__ style_w,
                        const float* __restrict__ style_b,
                        const float* __restrict__ weight,
                        float* __restrict__ s,
                        short* __restrict__ wsh,
                        float* __restrict__ G) {
  const int blk = blockIdx.x;
  const int tid = threadIdx.x;
  if (blk < 16) {
    const int b = blk;
    const float* ct = c_trg + b * 128;
    const float* sw = style_w + tid * 128;
    float acc = 0.f;
#pragma unroll 4
    for (int d = 0; d < 128; ++d) acc += ct[d] * sw[d];
    s[b * 256 + tid] = acc * 0.08838834764831845f + style_b[tid];  // 1/sqrt(128)
  } else {
    const int idx = (blk - 16) * 256 + tid;  // co*256+ci
    const float* wsrc = weight + idx * 9;    // 9 contiguous taps
    float g = 0.f;
#pragma unroll
    for (int t = 0; t < 9; ++t) {
      float v = wsrc[t] * 0.020833333333333332f;  // 1/sqrt(2304)
      g += v * v;
      wsh[t * 65536 + idx] = (short)f2bf(v);
    }
    G[idx] = g;
  }
}

// ---------------- kernel 2: y = s*x transpose + border zero + demod (fused grid) ----
__global__ void xpose_k(const float* __restrict__ x,
                        const float* __restrict__ s,
                        const float* __restrict__ G,
                        short* __restrict__ xpad,
                        float* __restrict__ demod) {
  __shared__ float tile[64][65];
  const int bid = blockIdx.x;
  const int tid = threadIdx.x;
  if (bid >= 4112) {
    // demod: block = b*256+co
    const int id = bid - 4112;
    const int b = id >> 8, co = id & 255;
    const float sv = s[b * 256 + tid];
    float ss = G[co * 256 + tid] * sv * sv;
#pragma unroll
    for (int o = 32; o; o >>= 1) ss += __shfl_down(ss, o);
    __shared__ float red[4];
    if ((tid & 63) == 0) red[tid >> 6] = ss;
    __syncthreads();
    if (tid == 0) demod[id] = rsqrtf(red[0] + red[1] + red[2] + red[3] + 1e-8f);
    return;
  }
  if (bid >= 4096) {
    const int b = bid - 4096;
    char* base = (char*)xpad + b * 66 * 66 * 512;
    const i32x4 z = {0, 0, 0, 0};
    for (int i = tid; i < 4224; i += 256) {
      const int r = i >= 2112;
      const int off = r * (65 * 66 * 512) + (i - r * 2112) * 16;
      *(i32x4*)(base + off) = z;
    }
    for (int i = tid; i < 4096; i += 256) {
      const int h = 1 + (i >> 6);
      const int side = (i >> 5) & 1;
      const int j = i & 31;
      *(i32x4*)(base + (h * 66 + side * 65) * 512 + j * 16) = z;
    }
    return;
  }
  const int ct = bid & 3;
  const int h = (bid >> 2) & 63;
  const int b = bid >> 8;
  const int w = tid & 63, cl = tid >> 6;
  const float* src = x + ((b * 256 + ct * 64) * 64 + h) * 64;
#pragma unroll
  for (int i = 0; i < 16; ++i) {
    int c = i * 4 + cl;
    tile[c][w] = src[c * 4096 + w];
  }
  const int cp = tid & 31;
  const float s0 = s[b * 256 + ct * 64 + cp * 2];
  const float s1 = s[b * 256 + ct * 64 + cp * 2 + 1];
  __syncthreads();
  short* dst = xpad + ((b * 66 + h + 1) * 66 + 1) * 256 + ct * 64;
#pragma unroll
  for (int i = 0; i < 8; ++i) {
    int idx = i * 256 + tid;
    int w2 = idx >> 5;  // 0..63
    unsigned int u = (unsigned int)f2bf(tile[cp * 2][w2] * s0) |
                     ((unsigned int)f2bf(tile[cp * 2 + 1][w2] * s1) << 16);
    *(unsigned int*)(dst + w2 * 256 + cp * 2) = u;
  }
}

// ---------------- kernel 3: implicit-GEMM conv, 256x256, BK=64, drift, UNPINNED -----
// 512 thr = 8 waves (2M x 4N), wave tile 128x64. LDS = 2 dbuf x (A 32K + B 32K).
// 36 K-tiles (tap 0..8 x cc 0..3). ONE sync point per tile (vmcnt(0)+barrier+SB).
// r10 change vs r7: NO intra-tile lgkmcnt(0)/sched_barrier pins. The ds_reads
// are plain C++ loads, so the compiler tracks data deps and emits fine-grained
// COUNTED lgkmcnt(N) waits (m97 asm behavior) -> each MFMA group starts as soon
// as its own operands land, its issue overlapping the tail of the read burst
// instead of a full LDS drain. setprio kept around MFMA clusters; program order
// reads -> stage -> MFMA preserved so staging still issues early.
// Race-freedom unchanged: stage(t+1) targets buf (t+1)&1 = tile t-1's buffer;
// every wave's reads of t-1 were data-dep-retired before it reached this tile's
// top barrier; the top vmcnt(0)+barrier publishes all waves' stage(t) writes.
// T1: XCD swizzle (grid 256) -> 2 samples per XCD L2.
// T2: XOR swizzle byte ^= ((row&7)<<4): linear LDS dest, inverse-swizzled
//     global source, swizzled ds_read; 16x16 frag rows span lane&15 -> 2-way
//     bank aliasing max = free (measured 0 conflicts).
__global__ __launch_bounds__(512, 2) void conv_k(const short* __restrict__ xpad,
                                                 const short* __restrict__ wsh,
                                                 const float* __restrict__ demod,
                                                 float* __restrict__ out) {
  extern __shared__ __align__(16) char lds[];  // 131072 B

  const int tid = threadIdx.x;
  const int lane = tid & 63;
  const int wid = tid >> 6;
  const int wm = wid >> 2;   // 0..1 : cout half
  const int wn = wid & 3;    // 0..3 : pixel quarter (output row r0+wn)

  const int orig = blockIdx.x;
  const int bid = (orig & 7) * 32 + (orig >> 3);  // T1
  const int b = bid >> 4;
  const int r0 = (bid & 15) * 4;  // 4 output rows per block

  // staging: per K-tile 8 x 16B loads/thread (A j0-3, B j0-3).
  // load j covers LDS rows j*64 + t3, byte col (tid&7)*16 (linear dest);
  // source col pre-swizzled: c16 ^ ((row&7)<<4), row&7 == t3&7.
  const int t3 = tid >> 3;
  const int c16 = (tid & 7) * 16;
  const int swzc = c16 ^ ((t3 & 7) << 4);
  int aO[4], bO[4];
#pragma unroll
  for (int j = 0; j < 4; ++j) {
    aO[j] = (j * 64 + t3) * 512 + swzc;                   // + tap*131072 + cc*128
    bO[j] = ((b * 66 + r0 + j) * 66 + t3) * 512 + swzc;   // + (dh*66+dw)*512 + cc*128
  }
  const char* wB = (const char*)wsh;
  const char* xB = (const char*)xpad;

  auto stageA = [&](int ts) {
    const int tap = ts >> 2, cc = ts & 3;
    const int aAdd = tap * 131072 + cc * 128;
    char* d = lds + (ts & 1) * 65536;
#pragma unroll
    for (int j = 0; j < 4; ++j)
      GLOAD_LDS16(wB + aAdd + aO[j], d + j * 8192 + tid * 16);
  };
  auto stageB = [&](int ts) {
    const int tap = ts >> 2, cc = ts & 3;
    const int dh = (tap * 11) >> 5;  // tap/3
    const int bAdd = (dh * 66 + (tap - dh * 3)) * 512 + cc * 128;
    char* d = lds + (ts & 1) * 65536 + 32768;
#pragma unroll
    for (int j = 0; j < 4; ++j)
      GLOAD_LDS16(xB + bAdd + bO[j], d + j * 8192 + tid * 16);
  };

  // T2 read side: col_read = col ^ ((row&7)<<4); row&7 == lane&7 everywhere.
  const int xall = (lane & 7) << 4;
  const int xl = xall & 0x30;
  const int xh = xall & 0x40;
  const int colR = (((lane >> 4) << 4) ^ xl);
  const int ko0 = xh;
  const int ko1 = 64 ^ xh;
  const int aRdBase = (wm * 128 + (lane & 15)) * 128 + colR;
  const int bRdBase = 32768 + (wn * 64 + (lane & 15)) * 128 + colR;

  f32x4 acc[8][4] = {};

  stageA(0);
  stageB(0);

  for (int t = 0; t < 36; ++t) {
    // single sync point per K-tile
    asm volatile("s_waitcnt vmcnt(0)" ::: "memory");
    __builtin_amdgcn_s_barrier();
    __builtin_amdgcn_sched_barrier(0);

    const char* Ab = lds + (t & 1) * 65536 + aRdBase;
    const char* Bb = lds + (t & 1) * 65536 + bRdBase;
    bf16x8 af[4][2], bq[2][2], bq2[2][2];

    // ---------- group 1 : reads A0-3, B0-1 ; stage A(t+1) ; MFMA (m0-3 x n0-1) -----
#pragma unroll
    for (int m = 0; m < 4; ++m) {
      af[m][0] = *(const bf16x8*)(Ab + m * 2048 + ko0);
      af[m][1] = *(const bf16x8*)(Ab + m * 2048 + ko1);
    }
#pragma unroll
    for (int n = 0; n < 2; ++n) {
      bq[n][0] = *(const bf16x8*)(Bb + n * 2048 + ko0);
      bq[n][1] = *(const bf16x8*)(Bb + n * 2048 + ko1);
    }
    if (t + 1 < 36) stageA(t + 1);
    __builtin_amdgcn_s_setprio(1);
#pragma unroll
    for (int m = 0; m < 4; ++m)
#pragma unroll
      for (int n = 0; n < 2; ++n) {
        acc[m][n] = __builtin_amdgcn_mfma_f32_16x16x32_bf16(af[m][0], bq[n][0], acc[m][n], 0, 0, 0);
        acc[m][n] = __builtin_amdgcn_mfma_f32_16x16x32_bf16(af[m][1], bq[n][1], acc[m][n], 0, 0, 0);
      }
    __builtin_amdgcn_s_setprio(0);

    // ---------- group 2 : reads B2-3 ; stage B(t+1) ; MFMA (m0-3 x n2-3) -----------
#pragma unroll
    for (int n = 0; n < 2; ++n) {
      bq2[n][0] = *(const bf16x8*)(Bb + (n + 2) * 2048 + ko0);
      bq2[n][1] = *(const bf16x8*)(Bb + (n + 2) * 2048 + ko1);
    }
    if (t + 1 < 36) stageB(t + 1);
    __builtin_amdgcn_s_setprio(1);
#pragma unroll
    for (int m = 0; m < 4; ++m)
#pragma unroll
      for (int n = 0; n < 2; ++n) {
        acc[m][n + 2] = __builtin_amdgcn_mfma_f32_16x16x32_bf16(af[m][0], bq2[n][0], acc[m][n + 2], 0, 0, 0);
        acc[m][n + 2] = __builtin_amdgcn_mfma_f32_16x16x32_bf16(af[m][1], bq2[n][1], acc[m][n + 2], 0, 0, 0);
      }
    __builtin_amdgcn_s_setprio(0);

    // ---------- group 3 : reads A4-7 ; MFMA (m4-7 x n0-3) --------------------------
#pragma unroll
    for (int m = 0; m < 4; ++m) {
      af[m][0] = *(const bf16x8*)(Ab + (m + 4) * 2048 + ko0);
      af[m][1] = *(const bf16x8*)(Ab + (m + 4) * 2048 + ko1);
    }
    __builtin_amdgcn_s_setprio(1);
#pragma unroll
    for (int m = 0; m < 4; ++m)
#pragma unroll
      for (int n = 0; n < 2; ++n) {
        acc[m + 4][n] = __builtin_amdgcn_mfma_f32_16x16x32_bf16(af[m][0], bq[n][0], acc[m + 4][n], 0, 0, 0);
        acc[m + 4][n] = __builtin_amdgcn_mfma_f32_16x16x32_bf16(af[m][1], bq[n][1], acc[m + 4][n], 0, 0, 0);
        acc[m + 4][n + 2] = __builtin_amdgcn_mfma_f32_16x16x32_bf16(af[m][0], bq2[n][0], acc[m + 4][n + 2], 0, 0, 0);
        acc[m + 4][n + 2] = __builtin_amdgcn_mfma_f32_16x16x32_bf16(af[m][1], bq2[n][1], acc[m + 4][n + 2], 0, 0, 0);
      }
    __builtin_amdgcn_s_setprio(0);
    asm volatile("" ::: "memory");
  }

  // epilogue: scale by demod[b][cout], store fp32 NCHW.
  const int pc = lane & 15;
  const int rOff = (lane >> 4) * 4;
  const int h = r0 + wn;
#pragma unroll
  for (int m = 0; m < 8; ++m) {
#pragma unroll
    for (int r = 0; r < 4; ++r) {
      const int co = wm * 128 + m * 16 + rOff + r;
      const float dm = demod[(b << 8) + co];
      float* orow = out + (((b << 8) + co) << 12) + (h << 6);
#pragma unroll
      for (int n = 0; n < 4; ++n) {
        orow[n * 16 + pc] = acc[m][n][r] * dm;
      }
    }
  }
}

// ---------------- launcher ----------------
extern "C" void kernel_launch(void* const* d_in, const int* in_sizes, int n_in,
                              void* d_out, int out_size, void* d_ws, size_t ws_size,
                              hipStream_t stream) {
  const float* x       = (const float*)d_in[0];
  // d_in[1] = c_src (unused by reference)
  const float* c_trg   = (const float*)d_in[2];
  const float* style_w = (const float*)d_in[3];
  const float* style_b = (const float*)d_in[4];
  const float* weight  = (const float*)d_in[5];
  float* out = (float*)d_out;

  char* ws = (char*)d_ws;
  short* xpad  = (short*)(ws);
  short* wsh   = (short*)(ws + WSH_OFF);
  float* s     = (float*)(ws + S_OFF);
  float* G     = (float*)(ws + G_OFF);
  float* demod = (float*)(ws + DEMOD_OFF);

  hipFuncSetAttribute((const void*)conv_k,
                      hipFuncAttributeMaxDynamicSharedMemorySize, 131072);

  prep1_k<<<272, 256, 0, stream>>>(c_trg, style_w, style_b, weight, s, wsh, G);
  xpose_k<<<8208, 256, 0, stream>>>(x, s, G, xpad, demod);
  conv_k<<<256, 512, 131072, stream>>>(xpad, wsh, demod, out);
}